// Round 6
// baseline (1930.079 us; speedup 1.0000x reference)
//
#include <hip/hip_runtime.h>
#include <hip/hip_bf16.h>
#include <hip/hip_cooperative_groups.h>

namespace cg = cooperative_groups;

#define NB   8      // batches
#define NP   4096   // points per batch
#define KNN  20     // neighbors
#define COUT 64     // output channels
#define BLK  128    // threads per block (2 waves)
#define BPB  (NP / BLK)   // 32 blocks per batch
#define NBLK (NB * BPB)   // 256 blocks total -> 1 per CU, cooperative-safe
#define NMOM 14     // 4 first + 10 second moments of feat=(dx,dy,dz,dist)

__global__ __launch_bounds__(BLK)
void lfa_kernel(const float* __restrict__ pos,
                const float* __restrict__ W,
                const float* __restrict__ bias,
                const float* __restrict__ gamma,
                const float* __restrict__ beta,
                float* __restrict__ out,          // f32 inputs, f32 output
                float* __restrict__ mom) {
    __shared__ float sx[NP], sy[NP], sz[NP];      // 48 KB (64 KB/WG cap!)
    __shared__ float sWp[COUT][4];                // folded W' = W * gamma/sigma
    __shared__ float sbp[COUT];                   // folded b'
    __shared__ float sred[NMOM][BLK / 64];        // cross-wave reduce scratch

    const int b = blockIdx.x / BPB;
    const int n = (blockIdx.x % BPB) * BLK + threadIdx.x;   // my query point
    const float* pb = pos + (size_t)b * NP * 3;

    // ---- stage pos[b] into LDS ----
    for (int i = threadIdx.x; i < NP; i += BLK) {
        sx[i] = pb[3 * i + 0];
        sy[i] = pb[3 * i + 1];
        sz[i] = pb[3 * i + 2];
    }
    __syncthreads();

    const float qx = sx[n], qy = sy[n], qz = sz[n];
    // sq = np.sum(pos*pos, -1): separate ufuncs -> rounded muls, serial adds.
    // Contraction across the ufunc boundary is impossible: plain is certain.
    const float qsq = __fadd_rn(__fadd_rn(__fmul_rn(qx, qx), __fmul_rn(qy, qy)),
                                __fmul_rn(qz, qz));

    // ---- phase 1: replicate the reference's f32 expanded-form d2.
    // dot: numpy einsum contig_two scalar tail (count=3 < SIMD width),
    // compiled in the FMA dispatch unit with fp-contract=fast ->
    // accum = fma(a[i],b[i],accum), i ascending; first step == rounded mul.
    // (XLA/Eigen/BLAS k-ascending FMA kernels produce identical bits.)
    // d2 = (sq_n + sq_m) - 2*dot: 2*dot exact, so contraction-immune.
    // Sorted-ascending top-20, med3 shift-insert: strict '<' gate +
    // insert-after-equals == top_k's lowest-index-first tie-break.
    float bd[KNN];
    int   bi[KNN];
#pragma unroll
    for (int j = 0; j < KNN; ++j) { bd[j] = 3.4e38f; bi[j] = 0x7fffffff; }

#pragma unroll 4
    for (int m = 0; m < NP; ++m) {
        const float cx = sx[m], cy = sy[m], cz = sz[m];
        const float csq = __fadd_rn(
            __fadd_rn(__fmul_rn(cx, cx), __fmul_rn(cy, cy)), __fmul_rn(cz, cz));
        const float dot = fmaf(qz, cz, fmaf(qy, cy, __fmul_rn(qx, cx)));
        const float d2 = __fsub_rn(__fadd_rn(qsq, csq),
                                   __fmul_rn(2.0f, dot));
        if (m != n && d2 < bd[KNN - 1]) {
            // descending shift-insert; each step uses ORIGINAL bd[j-1], bd[j]
#pragma unroll
            for (int j = KNN - 1; j >= 1; --j) {
                const bool shift = d2 < bd[j - 1];
                const bool ins   = !shift && (d2 < bd[j]);
                bi[j] = shift ? bi[j - 1] : (ins ? m : bi[j]);
                bd[j] = fminf(fmaxf(bd[j - 1], d2), bd[j]);   // med3
            }
            if (d2 < bd[0]) { bi[0] = m; bd[0] = d2; }
        }
    }

    // ---- edge features (f32, non-contracted like the reference) ----
    float fx[KNN], fy[KNN], fz[KNN], fd[KNN];
#pragma unroll
    for (int j = 0; j < KNN; ++j) {
        const int m = bi[j];
        const float dx = __fsub_rn(sx[m], qx);
        const float dy = __fsub_rn(sy[m], qy);
        const float dz = __fsub_rn(sz[m], qz);
        fx[j] = dx; fy[j] = dy; fz[j] = dz;
        fd[j] = sqrtf(__fadd_rn(
            __fadd_rn(__fmul_rn(dx, dx), __fmul_rn(dy, dy)),
            __fmul_rn(dz, dz)));
    }

    // ---- feat moments for the analytic BatchNorm ----
    float s1x = 0, s1y = 0, s1z = 0, s1d = 0;
    float mxx = 0, mxy = 0, mxz = 0, mxd = 0;
    float myy = 0, myz = 0, myd = 0;
    float mzz = 0, mzd = 0, mdd = 0;
#pragma unroll
    for (int j = 0; j < KNN; ++j) {
        const float dx = fx[j], dy = fy[j], dz = fz[j], dd = fd[j];
        s1x += dx; s1y += dy; s1z += dz; s1d += dd;
        mxx += dx * dx; mxy += dx * dy; mxz += dx * dz; mxd += dx * dd;
        myy += dy * dy; myz += dy * dz; myd += dy * dd;
        mzz += dz * dz; mzd += dz * dd; mdd += dd * dd;
    }
    {
        float vals[NMOM] = {s1x, s1y, s1z, s1d,
                            mxx, mxy, mxz, mxd, myy, myz, myd, mzz, mzd, mdd};
#pragma unroll
        for (int t = 0; t < NMOM; ++t) {
            float v = vals[t];
            for (int off = 32; off > 0; off >>= 1) v += __shfl_down(v, off);
            if ((threadIdx.x & 63) == 0) sred[t][threadIdx.x >> 6] = v;
        }
        __syncthreads();
        if (threadIdx.x < NMOM) {
            float tot = 0.f;
            for (int w = 0; w < BLK / 64; ++w) tot += sred[threadIdx.x][w];
            atomicAdd(&mom[threadIdx.x], tot);
        }
    }

    cg::this_grid().sync();

    // ---- phase 2: fold BN into W', b' (redundant per block; 64 threads) ----
    if (threadIdx.x < COUT) {
        const int o = threadIdx.x;
        double S1[4], s2v[10];
#pragma unroll
        for (int t = 0; t < 4; ++t)
            S1[t] = (double)__hip_atomic_load(&mom[t], __ATOMIC_RELAXED,
                                              __HIP_MEMORY_SCOPE_AGENT);
#pragma unroll
        for (int t = 0; t < 10; ++t)
            s2v[t] = (double)__hip_atomic_load(&mom[4 + t], __ATOMIC_RELAXED,
                                               __HIP_MEMORY_SCOPE_AGENT);
        const double M = (double)NB * NP * KNN;
        double mean[4];
#pragma unroll
        for (int c = 0; c < 4; ++c) mean[c] = S1[c] / M;
        double E2[4][4];
        E2[0][0] = s2v[0]; E2[0][1] = E2[1][0] = s2v[1];
        E2[0][2] = E2[2][0] = s2v[2]; E2[0][3] = E2[3][0] = s2v[3];
        E2[1][1] = s2v[4]; E2[1][2] = E2[2][1] = s2v[5];
        E2[1][3] = E2[3][1] = s2v[6];
        E2[2][2] = s2v[7]; E2[2][3] = E2[3][2] = s2v[8];
        E2[3][3] = s2v[9];

        double w[4];
#pragma unroll
        for (int c = 0; c < 4; ++c) w[c] = (double)W[o * 4 + c];
        const double bo = (double)bias[o];
        double mu = bo;
#pragma unroll
        for (int c = 0; c < 4; ++c) mu += w[c] * mean[c];
        double var = 0.0;
#pragma unroll
        for (int c = 0; c < 4; ++c)
#pragma unroll
            for (int c2 = 0; c2 < 4; ++c2)
                var += w[c] * w[c2] * (E2[c][c2] / M - mean[c] * mean[c2]);
        const double scale = (double)gamma[o] / sqrt(var + 1e-5);
#pragma unroll
        for (int c = 0; c < 4; ++c) sWp[o][c] = (float)(w[c] * scale);
        sbp[o] = (float)((bo - mu) * scale + (double)beta[o]);
    }
    __syncthreads();

    // ---- phase 3: per-edge linear + ReLU, mean over k, f32 store ----
    float* ob = out + ((size_t)b * NP + n) * COUT;
    const float inv = 1.0f / (float)KNN;
#pragma unroll
    for (int o = 0; o < COUT; o += 4) {
        float acc[4] = {0.f, 0.f, 0.f, 0.f};
#pragma unroll
        for (int q = 0; q < 4; ++q) {
            const float w0 = sWp[o + q][0], w1 = sWp[o + q][1];
            const float w2 = sWp[o + q][2], w3 = sWp[o + q][3];
            const float bb = sbp[o + q];
            float a = 0.f;
#pragma unroll
            for (int j = 0; j < KNN; ++j) {
                float y = fmaf(fx[j], w0,
                          fmaf(fy[j], w1, fmaf(fz[j], w2, fmaf(fd[j], w3, bb))));
                a += fmaxf(y, 0.f);
            }
            acc[q] = a * inv;
        }
        float4 p = {acc[0], acc[1], acc[2], acc[3]};
        *reinterpret_cast<float4*>(ob + o) = p;
    }
}

extern "C" void kernel_launch(void* const* d_in, const int* in_sizes, int n_in,
                              void* d_out, int out_size, void* d_ws, size_t ws_size,
                              hipStream_t stream) {
    (void)in_sizes; (void)n_in; (void)out_size; (void)ws_size;
    const float* pos   = (const float*)d_in[1];   // d_in[0] = x (unused by math)
    const float* W     = (const float*)d_in[2];
    const float* bias  = (const float*)d_in[3];
    const float* gamma = (const float*)d_in[4];
    const float* beta  = (const float*)d_in[5];
    float* out = (float*)d_out;
    float* mom = (float*)d_ws;

    hipMemsetAsync(mom, 0, NMOM * sizeof(float), stream);

    void* args[] = {(void*)&pos, (void*)&W, (void*)&bias, (void*)&gamma,
                    (void*)&beta, (void*)&out, (void*)&mom};
    hipLaunchCooperativeKernel((void*)lfa_kernel, dim3(NBLK), dim3(BLK),
                               args, 0, stream);
}

// Round 7
// 1418.431 us; speedup vs baseline: 1.3607x; 1.3607x over previous
//
#include <hip/hip_runtime.h>

#define NB    8       // batches
#define NP    4096    // points per batch
#define KNN   20      // neighbors
#define COUT  64      // output channels
#define S     4       // candidate splits per query (interleaved stride-S)
#define BLK   256     // threads per block (4 waves)
#define QPB   (BLK / S)          // 64 queries per block
#define BPB   (NP / QPB)         // 64 blocks per batch
#define NBLK1 (NB * BPB)         // 512 blocks -> 2 blocks/CU, 8 waves/CU
#define NBLK2 ((NB * NP * 4) / BLK)   // 512 blocks (4 threads per query)
#define NMOM  14      // 4 first + 10 second moments of feat=(dx,dy,dz,dist)
#define LCAP  32      // padded list length for bitonic merge

typedef unsigned long long u64;
typedef unsigned int u32;

// key = (bits(d2) << 12) | idx  — monotone in d2 (d2 >= 0), ties broken by
// lower idx first == exact lax.top_k(-d2) ordering. idx < 4096 fits 12 bits.
__device__ __forceinline__ u64 kpack(float d2, u32 m) {
    return ((u64)__float_as_uint(d2) << 12) | m;
}
#define KSENT kpack(1e30f, 0xFFFu)   // sentinel: larger than any real key

// ---------------- Kernel 1: KNN (split-scan + bitonic merge) + moments ----
__global__ __launch_bounds__(BLK)
void knn_kernel(const float* __restrict__ pos,
                unsigned short* __restrict__ idx_out,
                float* __restrict__ mom) {
    __shared__ float sx[NP], sy[NP], sz[NP];       // 48 KB
    __shared__ float sred[NMOM][BLK / 64];

    const int b  = blockIdx.x / BPB;
    const int t  = threadIdx.x;
    const int s  = t & (S - 1);                    // my split
    const int n  = (blockIdx.x % BPB) * QPB + (t >> 2);   // my query
    const float* pb = pos + (size_t)b * NP * 3;

    // stage pos[b] (thread i reads 12 contiguous bytes -> fully coalesced)
    for (int i = t; i < NP; i += BLK) {
        sx[i] = pb[3 * i + 0];
        sy[i] = pb[3 * i + 1];
        sz[i] = pb[3 * i + 2];
    }
    __syncthreads();

    const float qx = sx[n], qy = sy[n], qz = sz[n];
    const float qsq = __fadd_rn(__fadd_rn(__fmul_rn(qx, qx), __fmul_rn(qy, qy)),
                                __fmul_rn(qz, qz));

    // per-lane sorted top-20 over candidates m = i*S + s (ascending in-lane)
    u64 bd[LCAP];
#pragma unroll
    for (int j = 0; j < LCAP; ++j) bd[j] = KSENT;
    float g19 = 1e30f;                             // d2-part of bd[19]

#pragma unroll 4
    for (int i = 0; i < NP / S; ++i) {
        const int m = i * S + s;                   // 4 distinct banks, broadcast
        const float cx = sx[m], cy = sy[m], cz = sz[m];
        const float csq = __fadd_rn(
            __fadd_rn(__fmul_rn(cx, cx), __fmul_rn(cy, cy)), __fmul_rn(cz, cz));
        const float dot = fmaf(qz, cz, fmaf(qy, cy, __fmul_rn(qx, cx)));
        const float d2  = __fsub_rn(__fadd_rn(qsq, csq), __fmul_rn(2.0f, dot));
        if (m != n && d2 < g19) {                  // strict <: later idx loses ties
            const u64 key = kpack(d2, (u32)m);
#pragma unroll
            for (int j = KNN - 1; j >= 1; --j) {
                const bool sh = key < bd[j - 1];
                bd[j] = sh ? bd[j - 1] : (key < bd[j] ? key : bd[j]);
            }
            if (key < bd[0]) bd[0] = key;
            g19 = __uint_as_float((u32)(bd[KNN - 1] >> 12));
        }
    }

    // merge the 4 split lists (lanes s=0..3) in registers: for each round,
    // stage-1 keeps the 32 smallest of (mine ++ partner's) as a bitonic
    // sequence, then a 32-wide bitonic network re-sorts. All lanes converge
    // to the identical sorted global top-32; entries 0..19 are the answer.
#pragma unroll
    for (int r = 1; r <= 2; r <<= 1) {
#pragma unroll
        for (int j = 0; j < LCAP / 2; ++j) {
            const int k2 = LCAP - 1 - j;
            const u64 pa = (u64)__shfl_xor((long long)bd[k2], r); // partner bd[31-j]
            const u64 pc = (u64)__shfl_xor((long long)bd[j],  r); // partner bd[j]
            bd[j]  = bd[j]  < pa ? bd[j]  : pa;
            bd[k2] = bd[k2] < pc ? bd[k2] : pc;
        }
#pragma unroll
        for (int d = 16; d >= 1; d >>= 1) {
#pragma unroll
            for (int j = 0; j < LCAP; ++j) {
                if ((j & d) == 0) {
                    const u64 x = bd[j], y = bd[j + d];
                    bd[j]     = x < y ? x : y;
                    bd[j + d] = x < y ? y : x;
                }
            }
        }
    }

    // edge features: lane s handles j in [5s, 5s+5); store idx for kernel 2
    float fx[5], fy[5], fz[5], fd[5];
    unsigned short* ip = idx_out + ((size_t)b * NP + n) * KNN;
#pragma unroll
    for (int u = 0; u < 5; ++u) {
        const int j = s * 5 + u;
        const int m = (int)(bd[j] & 0xFFFull);
        ip[j] = (unsigned short)m;
        const float dx = __fsub_rn(sx[m], qx);
        const float dy = __fsub_rn(sy[m], qy);
        const float dz = __fsub_rn(sz[m], qz);
        fx[u] = dx; fy[u] = dy; fz[u] = dz;
        fd[u] = sqrtf(__fadd_rn(
            __fadd_rn(__fmul_rn(dx, dx), __fmul_rn(dy, dy)), __fmul_rn(dz, dz)));
    }

    // feat moments for the analytic BatchNorm (all lanes hold 5 real edges)
    float s1x = 0, s1y = 0, s1z = 0, s1d = 0;
    float mxx = 0, mxy = 0, mxz = 0, mxd = 0;
    float myy = 0, myz = 0, myd = 0;
    float mzz = 0, mzd = 0, mdd = 0;
#pragma unroll
    for (int u = 0; u < 5; ++u) {
        const float dx = fx[u], dy = fy[u], dz = fz[u], dd = fd[u];
        s1x += dx; s1y += dy; s1z += dz; s1d += dd;
        mxx += dx * dx; mxy += dx * dy; mxz += dx * dz; mxd += dx * dd;
        myy += dy * dy; myz += dy * dz; myd += dy * dd;
        mzz += dz * dz; mzd += dz * dd; mdd += dd * dd;
    }
    {
        float vals[NMOM] = {s1x, s1y, s1z, s1d,
                            mxx, mxy, mxz, mxd, myy, myz, myd, mzz, mzd, mdd};
#pragma unroll
        for (int tt = 0; tt < NMOM; ++tt) {
            float v = vals[tt];
            for (int off = 32; off > 0; off >>= 1) v += __shfl_down(v, off);
            if ((t & 63) == 0) sred[tt][t >> 6] = v;
        }
        __syncthreads();
        if (t < NMOM) {
            float tot = 0.f;
            for (int w = 0; w < BLK / 64; ++w) tot += sred[t][w];
            atomicAdd(&mom[t], tot);
        }
    }
}

// ---------------- Kernel 2: fold BN + per-edge linear + ReLU + mean ------
__global__ __launch_bounds__(BLK)
void out_kernel(const float* __restrict__ pos,
                const float* __restrict__ W,
                const float* __restrict__ bias,
                const float* __restrict__ gamma,
                const float* __restrict__ beta,
                const unsigned short* __restrict__ idx_in,
                const float* __restrict__ mom,
                float* __restrict__ out) {
    __shared__ float sWp[COUT][4];
    __shared__ float sbp[COUT];

    if (threadIdx.x < COUT) {
        const int o = threadIdx.x;
        double S1[4], s2v[10];
#pragma unroll
        for (int tt = 0; tt < 4; ++tt)  S1[tt]  = (double)mom[tt];
#pragma unroll
        for (int tt = 0; tt < 10; ++tt) s2v[tt] = (double)mom[4 + tt];
        const double M = (double)NB * NP * KNN;
        double mean[4];
#pragma unroll
        for (int c = 0; c < 4; ++c) mean[c] = S1[c] / M;
        double E2[4][4];
        E2[0][0] = s2v[0]; E2[0][1] = E2[1][0] = s2v[1];
        E2[0][2] = E2[2][0] = s2v[2]; E2[0][3] = E2[3][0] = s2v[3];
        E2[1][1] = s2v[4]; E2[1][2] = E2[2][1] = s2v[5];
        E2[1][3] = E2[3][1] = s2v[6];
        E2[2][2] = s2v[7]; E2[2][3] = E2[3][2] = s2v[8];
        E2[3][3] = s2v[9];
        double w[4];
#pragma unroll
        for (int c = 0; c < 4; ++c) w[c] = (double)W[o * 4 + c];
        const double bo = (double)bias[o];
        double mu = bo;
#pragma unroll
        for (int c = 0; c < 4; ++c) mu += w[c] * mean[c];
        double var = 0.0;
#pragma unroll
        for (int c = 0; c < 4; ++c)
#pragma unroll
            for (int c2 = 0; c2 < 4; ++c2)
                var += w[c] * w[c2] * (E2[c][c2] / M - mean[c] * mean[c2]);
        const double scale = (double)gamma[o] / sqrt(var + 1e-5);
#pragma unroll
        for (int c = 0; c < 4; ++c) sWp[o][c] = (float)(w[c] * scale);
        sbp[o] = (float)((bo - mu) * scale + (double)beta[o]);
    }
    __syncthreads();

    const int t  = threadIdx.x;
    const int gq = blockIdx.x * (BLK / 4) + (t >> 2);  // global query
    const int b  = gq / NP, n = gq % NP;
    const int c0 = (t & 3) * 16;                       // my 16 channels
    const float* pb = pos + (size_t)b * NP * 3;
    const float qx = pb[3 * n], qy = pb[3 * n + 1], qz = pb[3 * n + 2];

    float fx[KNN], fy[KNN], fz[KNN], fd[KNN];
    const unsigned short* ip = idx_in + (size_t)gq * KNN;
#pragma unroll
    for (int j = 0; j < KNN; ++j) {
        const int m = ip[j];
        const float dx = __fsub_rn(pb[3 * m], qx);
        const float dy = __fsub_rn(pb[3 * m + 1], qy);
        const float dz = __fsub_rn(pb[3 * m + 2], qz);
        fx[j] = dx; fy[j] = dy; fz[j] = dz;
        fd[j] = sqrtf(__fadd_rn(
            __fadd_rn(__fmul_rn(dx, dx), __fmul_rn(dy, dy)), __fmul_rn(dz, dz)));
    }

    float* ob = out + (size_t)gq * COUT + c0;
    const float inv = 1.0f / (float)KNN;
#pragma unroll
    for (int o = 0; o < 16; o += 4) {
        float acc[4];
#pragma unroll
        for (int q = 0; q < 4; ++q) {
            const float w0 = sWp[c0 + o + q][0], w1 = sWp[c0 + o + q][1];
            const float w2 = sWp[c0 + o + q][2], w3 = sWp[c0 + o + q][3];
            const float bb = sbp[c0 + o + q];
            float a = 0.f;
#pragma unroll
            for (int j = 0; j < KNN; ++j) {
                float y = fmaf(fx[j], w0,
                          fmaf(fy[j], w1, fmaf(fz[j], w2, fmaf(fd[j], w3, bb))));
                a += fmaxf(y, 0.f);
            }
            acc[q] = a * inv;
        }
        float4 p = {acc[0], acc[1], acc[2], acc[3]};
        *reinterpret_cast<float4*>(ob + o) = p;
    }
}

extern "C" void kernel_launch(void* const* d_in, const int* in_sizes, int n_in,
                              void* d_out, int out_size, void* d_ws, size_t ws_size,
                              hipStream_t stream) {
    (void)in_sizes; (void)n_in; (void)out_size; (void)ws_size;
    const float* pos   = (const float*)d_in[1];   // d_in[0] = x (unused by math)
    const float* W     = (const float*)d_in[2];
    const float* bias  = (const float*)d_in[3];
    const float* gamma = (const float*)d_in[4];
    const float* beta  = (const float*)d_in[5];
    float* out = (float*)d_out;

    float* mom = (float*)d_ws;                                   // 14 floats
    unsigned short* idxws = (unsigned short*)((char*)d_ws + 64); // 1.31 MB

    hipMemsetAsync(mom, 0, NMOM * sizeof(float), stream);
    knn_kernel<<<NBLK1, BLK, 0, stream>>>(pos, idxws, mom);
    out_kernel<<<NBLK2, BLK, 0, stream>>>(pos, W, bias, gamma, beta,
                                          idxws, mom, out);
}

// Round 8
// 659.881 us; speedup vs baseline: 2.9249x; 2.1495x over previous
//
#include <hip/hip_runtime.h>

#define NB    8       // batches
#define NP    4096    // points per batch
#define KNN   20      // neighbors
#define COUT  64      // output channels
#define S     4       // candidate splits per query
#define BLK   256     // threads per block (4 waves)
#define QPB   (BLK / S)          // 64 queries per block
#define BPB   (NP / QPB)         // 64 blocks per batch
#define NBLK1 (NB * BPB)         // 512 blocks
#define NBLK2 ((NB * NP * 4) / BLK)   // 512 blocks (4 threads per query)
#define NMOM  14
#define LCAP  32      // padded list length for bitonic merge
#define FBIG  3.402823466e38f

typedef unsigned long long u64;
typedef unsigned int u32;

// strict-< sorted insert (ascending), insert-after-equals == lax.top_k's
// lowest-index-first tie-break (verified rounds 4/6). Inactive lanes feed
// d=FBIG -> provable no-op (strict < fails everywhere).
__device__ __forceinline__ void ins20(float d, u32 mi,
                                      float* __restrict__ bd,
                                      u32* __restrict__ bi) {
#pragma unroll
    for (int j = KNN - 1; j >= 1; --j) {
        const bool sh  = d < bd[j - 1];
        const bool in_ = !sh && (d < bd[j]);
        bi[j] = sh ? bi[j - 1] : (in_ ? mi : bi[j]);
        bd[j] = fminf(fmaxf(bd[j - 1], d), bd[j]);   // med3
    }
    if (d < bd[0]) { bi[0] = mi; bd[0] = d; }
}

// ---------------- Kernel 1: KNN (buffered scan + bitonic merge) ----------
__global__ __launch_bounds__(BLK, 2)
void knn_kernel(const float* __restrict__ pos,
                unsigned short* __restrict__ idx_out,
                float* __restrict__ mom) {
    __shared__ float4 sp[NP];                      // 64 KB: (x, y, z, csq)

    const int b = blockIdx.x / BPB;
    const int t = threadIdx.x;
    const int s = t & (S - 1);                     // my split
    const int n = (blockIdx.x % BPB) * QPB + (t >> 2);   // my query
    const float* pb = pos + (size_t)b * NP * 3;

    // stage pos[b]; csq computed with the reference's exact op sequence
    for (int i = t; i < NP; i += BLK) {
        const float x = pb[3 * i], y = pb[3 * i + 1], z = pb[3 * i + 2];
        const float csq = __fadd_rn(
            __fadd_rn(__fmul_rn(x, x), __fmul_rn(y, y)), __fmul_rn(z, z));
        sp[i] = make_float4(x, y, z, csq);
    }
    __syncthreads();

    const float4 q = sp[n];                        // qx,qy,qz,qsq (same bits)

    float bd[KNN];
    u32   bi[KNN];
#pragma unroll
    for (int j = 0; j < KNN; ++j) { bd[j] = FBIG; bi[j] = 0xFFFu; }
    float g19 = FBIG;
    float b0d = 0.f, b1d = 0.f; u32 b0i = 0, b1i = 0; int cnt = 0;

#pragma unroll 4
    for (int i = 0; i < NP / S; ++i) {
        const int m = (i << 2) | s;
        const float4 c = sp[m];                    // 4 distinct addrs: broadcast
        const float dot = fmaf(q.z, c.z, fmaf(q.y, c.y, __fmul_rn(q.x, c.x)));
        const float d2  = __fsub_rn(__fadd_rn(q.w, c.w), __fmul_rn(2.0f, dot));
        const bool acc = (m != n) && (d2 < g19);   // strict <: ties keep incumbent
        const bool a0 = acc && (cnt == 0);
        const bool a1 = acc && (cnt == 1);
        b0d = a0 ? d2 : b0d;  b0i = a0 ? (u32)m : b0i;
        b1d = a1 ? d2 : b1d;  b1i = a1 ? (u32)m : b1i;
        cnt += (int)acc;
        if (__ballot(cnt == 2)) {                  // wave-wide amortized flush
            ins20(cnt >= 1 ? b0d : FBIG, b0i, bd, bi);
            ins20(cnt == 2 ? b1d : FBIG, b1i, bd, bi);
            cnt = 0;
            g19 = bd[KNN - 1];
        }
    }
    // drain pending
    ins20(cnt >= 1 ? b0d : FBIG, b0i, bd, bi);
    ins20(cnt == 2 ? b1d : FBIG, b1i, bd, bi);

    // build merge keys: order-preserving float->uint flip (handles d2<0),
    // idx in low 12 bits = lowest-index-first ties (verified round 7)
    u64 key[LCAP];
#pragma unroll
    for (int j = 0; j < KNN; ++j) {
        u32 fb = __float_as_uint(bd[j]);
        fb ^= (u32)((int)fb >> 31) | 0x80000000u;
        key[j] = ((u64)fb << 12) | bi[j];
    }
#pragma unroll
    for (int j = KNN; j < LCAP; ++j) key[j] = ~0ull;

    // merge 4 split lists across lanes (round-7-verified bitonic merge)
#pragma unroll
    for (int r = 1; r <= 2; r <<= 1) {
#pragma unroll
        for (int j = 0; j < LCAP / 2; ++j) {
            const int k2 = LCAP - 1 - j;
            const u64 pa = (u64)__shfl_xor((long long)key[k2], r);
            const u64 pc = (u64)__shfl_xor((long long)key[j],  r);
            key[j]  = key[j]  < pa ? key[j]  : pa;
            key[k2] = key[k2] < pc ? key[k2] : pc;
        }
#pragma unroll
        for (int d = 16; d >= 1; d >>= 1) {
#pragma unroll
            for (int j = 0; j < LCAP; ++j) {
                if ((j & d) == 0) {
                    const u64 x = key[j], y = key[j + d];
                    key[j]     = x < y ? x : y;
                    key[j + d] = x < y ? y : x;
                }
            }
        }
    }

    // edge features: lane s handles j in [5s, 5s+5); store idx for kernel 2
    float fx[5], fy[5], fz[5], fd[5];
    unsigned short* ip = idx_out + ((size_t)b * NP + n) * KNN;
#pragma unroll
    for (int u = 0; u < 5; ++u) {
        const int j = s * 5 + u;
        const int m = (int)(key[j] & 0xFFFull);
        ip[j] = (unsigned short)m;
        const float4 c = sp[m];
        const float dx = __fsub_rn(c.x, q.x);
        const float dy = __fsub_rn(c.y, q.y);
        const float dz = __fsub_rn(c.z, q.z);
        fx[u] = dx; fy[u] = dy; fz[u] = dz;
        fd[u] = sqrtf(__fadd_rn(
            __fadd_rn(__fmul_rn(dx, dx), __fmul_rn(dy, dy)), __fmul_rn(dz, dz)));
    }

    // feat moments (wave shfl-reduce -> one atomic per wave per moment)
    float s1x = 0, s1y = 0, s1z = 0, s1d = 0;
    float mxx = 0, mxy = 0, mxz = 0, mxd = 0;
    float myy = 0, myz = 0, myd = 0;
    float mzz = 0, mzd = 0, mdd = 0;
#pragma unroll
    for (int u = 0; u < 5; ++u) {
        const float dx = fx[u], dy = fy[u], dz = fz[u], dd = fd[u];
        s1x += dx; s1y += dy; s1z += dz; s1d += dd;
        mxx += dx * dx; mxy += dx * dy; mxz += dx * dz; mxd += dx * dd;
        myy += dy * dy; myz += dy * dz; myd += dy * dd;
        mzz += dz * dz; mzd += dz * dd; mdd += dd * dd;
    }
    {
        float vals[NMOM] = {s1x, s1y, s1z, s1d,
                            mxx, mxy, mxz, mxd, myy, myz, myd, mzz, mzd, mdd};
#pragma unroll
        for (int tt = 0; tt < NMOM; ++tt) {
            float v = vals[tt];
#pragma unroll
            for (int off = 32; off > 0; off >>= 1) v += __shfl_down(v, off);
            if ((t & 63) == 0) atomicAdd(&mom[tt], v);
        }
    }
}

// ---------------- Kernel 2: fold BN + per-edge linear + ReLU + mean ------
__global__ __launch_bounds__(BLK)
void out_kernel(const float* __restrict__ pos,
                const float* __restrict__ W,
                const float* __restrict__ bias,
                const float* __restrict__ gamma,
                const float* __restrict__ beta,
                const unsigned short* __restrict__ idx_in,
                const float* __restrict__ mom,
                float* __restrict__ out) {
    __shared__ float sWp[COUT][4];
    __shared__ float sbp[COUT];

    if (threadIdx.x < COUT) {
        const int o = threadIdx.x;
        double S1[4], s2v[10];
#pragma unroll
        for (int tt = 0; tt < 4; ++tt)  S1[tt]  = (double)mom[tt];
#pragma unroll
        for (int tt = 0; tt < 10; ++tt) s2v[tt] = (double)mom[4 + tt];
        const double M = (double)NB * NP * KNN;
        double mean[4];
#pragma unroll
        for (int c = 0; c < 4; ++c) mean[c] = S1[c] / M;
        double E2[4][4];
        E2[0][0] = s2v[0]; E2[0][1] = E2[1][0] = s2v[1];
        E2[0][2] = E2[2][0] = s2v[2]; E2[0][3] = E2[3][0] = s2v[3];
        E2[1][1] = s2v[4]; E2[1][2] = E2[2][1] = s2v[5];
        E2[1][3] = E2[3][1] = s2v[6];
        E2[2][2] = s2v[7]; E2[2][3] = E2[3][2] = s2v[8];
        E2[3][3] = s2v[9];
        double w[4];
#pragma unroll
        for (int c = 0; c < 4; ++c) w[c] = (double)W[o * 4 + c];
        const double bo = (double)bias[o];
        double mu = bo;
#pragma unroll
        for (int c = 0; c < 4; ++c) mu += w[c] * mean[c];
        double var = 0.0;
#pragma unroll
        for (int c = 0; c < 4; ++c)
#pragma unroll
            for (int c2 = 0; c2 < 4; ++c2)
                var += w[c] * w[c2] * (E2[c][c2] / M - mean[c] * mean[c2]);
        const double scale = (double)gamma[o] / sqrt(var + 1e-5);
#pragma unroll
        for (int c = 0; c < 4; ++c) sWp[o][c] = (float)(w[c] * scale);
        sbp[o] = (float)((bo - mu) * scale + (double)beta[o]);
    }
    __syncthreads();

    const int t  = threadIdx.x;
    const int gq = blockIdx.x * (BLK / 4) + (t >> 2);  // global query
    const int b  = gq / NP, n = gq % NP;
    const int c0 = (t & 3) * 16;                       // my 16 channels
    const float* pb = pos + (size_t)b * NP * 3;
    const float qx = pb[3 * n], qy = pb[3 * n + 1], qz = pb[3 * n + 2];

    float fx[KNN], fy[KNN], fz[KNN], fd[KNN];
    const unsigned short* ip = idx_in + (size_t)gq * KNN;
#pragma unroll
    for (int j = 0; j < KNN; ++j) {
        const int m = ip[j];
        const float dx = __fsub_rn(pb[3 * m], qx);
        const float dy = __fsub_rn(pb[3 * m + 1], qy);
        const float dz = __fsub_rn(pb[3 * m + 2], qz);
        fx[j] = dx; fy[j] = dy; fz[j] = dz;
        fd[j] = sqrtf(__fadd_rn(
            __fadd_rn(__fmul_rn(dx, dx), __fmul_rn(dy, dy)), __fmul_rn(dz, dz)));
    }

    float* ob = out + (size_t)gq * COUT + c0;
    const float inv = 1.0f / (float)KNN;
#pragma unroll
    for (int o = 0; o < 16; o += 4) {
        float acc[4];
#pragma unroll
        for (int q = 0; q < 4; ++q) {
            const float w0 = sWp[c0 + o + q][0], w1 = sWp[c0 + o + q][1];
            const float w2 = sWp[c0 + o + q][2], w3 = sWp[c0 + o + q][3];
            const float bb = sbp[c0 + o + q];
            float a = 0.f;
#pragma unroll
            for (int j = 0; j < KNN; ++j) {
                float y = fmaf(fx[j], w0,
                          fmaf(fy[j], w1, fmaf(fz[j], w2, fmaf(fd[j], w3, bb))));
                a += fmaxf(y, 0.f);
            }
            acc[q] = a * inv;
        }
        float4 p = {acc[0], acc[1], acc[2], acc[3]};
        *reinterpret_cast<float4*>(ob + o) = p;
    }
}

extern "C" void kernel_launch(void* const* d_in, const int* in_sizes, int n_in,
                              void* d_out, int out_size, void* d_ws, size_t ws_size,
                              hipStream_t stream) {
    (void)in_sizes; (void)n_in; (void)out_size; (void)ws_size;
    const float* pos   = (const float*)d_in[1];   // d_in[0] = x (unused by math)
    const float* W     = (const float*)d_in[2];
    const float* bias  = (const float*)d_in[3];
    const float* gamma = (const float*)d_in[4];
    const float* beta  = (const float*)d_in[5];
    float* out = (float*)d_out;

    float* mom = (float*)d_ws;                                   // 14 floats
    unsigned short* idxws = (unsigned short*)((char*)d_ws + 64); // 1.31 MB

    hipMemsetAsync(mom, 0, NMOM * sizeof(float), stream);
    knn_kernel<<<NBLK1, BLK, 0, stream>>>(pos, idxws, mom);
    out_kernel<<<NBLK2, BLK, 0, stream>>>(pos, W, bias, gamma, beta,
                                          idxws, mom, out);
}

// Round 11
// 652.465 us; speedup vs baseline: 2.9581x; 1.0114x over previous
//
#include <hip/hip_runtime.h>

#define NB    8       // batches
#define NP    4096    // points per batch
#define KNN   20      // neighbors
#define COUT  64      // output channels
#define S     4       // candidate splits per query  (ROUND-8 VERIFIED CONFIG)
#define BLK   256     // threads per block (4 waves)
#define QPB   (BLK / S)          // 64 queries per block
#define BPB   (NP / QPB)         // 64 blocks per batch
#define NBLK1 (NB * BPB)         // 512 blocks
#define NBLK2 ((NB * NP * 4) / BLK)   // 512 blocks (4 threads per query)
#define NMOM  14
#define LCAP  32      // padded list length for bitonic merge
#define FBIG  3.402823466e38f

typedef unsigned long long u64;
typedef unsigned int u32;

// strict-< sorted insert (ascending), insert-after-equals == lax.top_k's
// lowest-index-first tie-break (verified rounds 4/6/8). d=FBIG -> no-op.
__device__ __forceinline__ void ins20(float d, u32 mi,
                                      float* __restrict__ bd,
                                      u32* __restrict__ bi) {
#pragma unroll
    for (int j = KNN - 1; j >= 1; --j) {
        const bool sh  = d < bd[j - 1];
        const bool in_ = !sh && (d < bd[j]);
        bi[j] = sh ? bi[j - 1] : (in_ ? mi : bi[j]);
        bd[j] = fminf(fmaxf(bd[j - 1], d), bd[j]);   // med3
    }
    if (d < bd[0]) { bi[0] = mi; bd[0] = d; }
}

// ---------------- Kernel 1: KNN (round-8 scan/merge, static-j epilogue) --
__global__ __launch_bounds__(BLK, 2)
void knn_kernel(const float* __restrict__ pos,
                unsigned short* __restrict__ idx_out,
                float* __restrict__ mom) {
    __shared__ float4 sp[NP];                      // 64 KB: (x, y, z, csq)

    const int b = blockIdx.x / BPB;
    const int t = threadIdx.x;
    const int s = t & (S - 1);                     // my split
    const int n = (blockIdx.x % BPB) * QPB + (t >> 2);   // my query
    const float* pb = pos + (size_t)b * NP * 3;

    // stage pos[b]; csq computed with the reference's exact op sequence
    for (int i = t; i < NP; i += BLK) {
        const float x = pb[3 * i], y = pb[3 * i + 1], z = pb[3 * i + 2];
        const float csq = __fadd_rn(
            __fadd_rn(__fmul_rn(x, x), __fmul_rn(y, y)), __fmul_rn(z, z));
        sp[i] = make_float4(x, y, z, csq);
    }
    __syncthreads();

    const float4 q = sp[n];                        // qx,qy,qz,qsq (same bits)

    float bd[KNN];
    u32   bi[KNN];
#pragma unroll
    for (int j = 0; j < KNN; ++j) { bd[j] = FBIG; bi[j] = 0xFFFu; }
    float g19 = FBIG;                              // OWN-lane bound (round 8)
    float b0d = 0.f, b1d = 0.f; u32 b0i = 0, b1i = 0; int cnt = 0;

#pragma unroll 4
    for (int i = 0; i < NP / S; ++i) {
        const int m = (i << 2) | s;
        const float4 c = sp[m];                    // 4 distinct addrs: broadcast
        const float dot = fmaf(q.z, c.z, fmaf(q.y, c.y, __fmul_rn(q.x, c.x)));
        const float d2  = __fsub_rn(__fadd_rn(q.w, c.w), __fmul_rn(2.0f, dot));
        const bool acc = (m != n) && (d2 < g19);   // strict <: ties keep incumbent
        const bool a0 = acc && (cnt == 0);
        const bool a1 = acc && (cnt == 1);
        b0d = a0 ? d2 : b0d;  b0i = a0 ? (u32)m : b0i;
        b1d = a1 ? d2 : b1d;  b1i = a1 ? (u32)m : b1i;
        cnt += (int)acc;
        if (__ballot(cnt == 2)) {                  // wave-wide amortized flush
            ins20(cnt >= 1 ? b0d : FBIG, b0i, bd, bi);
            ins20(cnt == 2 ? b1d : FBIG, b1i, bd, bi);
            cnt = 0;
            g19 = bd[KNN - 1];
        }
    }
    // drain pending
    ins20(cnt >= 1 ? b0d : FBIG, b0i, bd, bi);
    ins20(cnt == 2 ? b1d : FBIG, b1i, bd, bi);

    // build merge keys: order-preserving float->uint flip,
    // idx in low 12 bits = lowest-index-first ties (verified rounds 7/8)
    u64 key[LCAP];
#pragma unroll
    for (int j = 0; j < KNN; ++j) {
        u32 fb = __float_as_uint(bd[j]);
        fb ^= (u32)((int)fb >> 31) | 0x80000000u;
        key[j] = ((u64)fb << 12) | bi[j];
    }
#pragma unroll
    for (int j = KNN; j < LCAP; ++j) key[j] = ~0ull;

    // merge 4 split lists across lanes (round-7/8-verified bitonic merge)
#pragma unroll
    for (int r = 1; r <= 2; r <<= 1) {
#pragma unroll
        for (int j = 0; j < LCAP / 2; ++j) {
            const int k2 = LCAP - 1 - j;
            const u64 pa = (u64)__shfl_xor((long long)key[k2], r);
            const u64 pc = (u64)__shfl_xor((long long)key[j],  r);
            key[j]  = key[j]  < pa ? key[j]  : pa;
            key[k2] = key[k2] < pc ? key[k2] : pc;
        }
#pragma unroll
        for (int d = 16; d >= 1; d >>= 1) {
#pragma unroll
            for (int j = 0; j < LCAP; ++j) {
                if ((j & d) == 0) {
                    const u64 x = key[j], y = key[j + d];
                    key[j]     = x < y ? x : y;
                    key[j + d] = x < y ? y : x;
                }
            }
        }
    }

    // ---- THE ONLY CHANGE vs round 8: static-j epilogue (no dynamic reg
    // indexing -> no scratch). All 4 group lanes hold identical sorted
    // key[0..19]; each j handled by all lanes, store predicated to one.
    unsigned short* ip = idx_out + ((size_t)b * NP + n) * KNN;
    float s1x = 0, s1y = 0, s1z = 0, s1d = 0;
    float mxx = 0, mxy = 0, mxz = 0, mxd = 0;
    float myy = 0, myz = 0, myd = 0;
    float mzz = 0, mzd = 0, mdd = 0;
#pragma unroll
    for (int j = 0; j < KNN; ++j) {
        const int m = (int)(key[j] & 0xFFFull);
        if ((j & 3) == s) ip[j] = (unsigned short)m;   // one lane per j
        const float4 c = sp[m];
        const float dx = __fsub_rn(c.x, q.x);
        const float dy = __fsub_rn(c.y, q.y);
        const float dz = __fsub_rn(c.z, q.z);
        const float dd = sqrtf(__fadd_rn(
            __fadd_rn(__fmul_rn(dx, dx), __fmul_rn(dy, dy)), __fmul_rn(dz, dz)));
        s1x += dx; s1y += dy; s1z += dz; s1d += dd;
        mxx += dx * dx; mxy += dx * dy; mxz += dx * dz; mxd += dx * dd;
        myy += dy * dy; myz += dy * dz; myd += dy * dd;
        mzz += dz * dz; mzd += dz * dd; mdd += dd * dd;
    }
    {
        // every query counted 4x (once per split lane) -> exact /4 after reduce
        float vals[NMOM] = {s1x, s1y, s1z, s1d,
                            mxx, mxy, mxz, mxd, myy, myz, myd, mzz, mzd, mdd};
#pragma unroll
        for (int tt = 0; tt < NMOM; ++tt) {
            float v = vals[tt];
#pragma unroll
            for (int off = 32; off > 0; off >>= 1) v += __shfl_down(v, off);
            if ((t & 63) == 0) atomicAdd(&mom[tt], v * 0.25f);
        }
    }
}

// ---------------- Kernel 2: round-8 verbatim -----------------------------
__global__ __launch_bounds__(BLK)
void out_kernel(const float* __restrict__ pos,
                const float* __restrict__ W,
                const float* __restrict__ bias,
                const float* __restrict__ gamma,
                const float* __restrict__ beta,
                const unsigned short* __restrict__ idx_in,
                const float* __restrict__ mom,
                float* __restrict__ out) {
    __shared__ float sWp[COUT][4];
    __shared__ float sbp[COUT];

    if (threadIdx.x < COUT) {
        const int o = threadIdx.x;
        double S1[4], s2v[10];
#pragma unroll
        for (int tt = 0; tt < 4; ++tt)  S1[tt]  = (double)mom[tt];
#pragma unroll
        for (int tt = 0; tt < 10; ++tt) s2v[tt] = (double)mom[4 + tt];
        const double M = (double)NB * NP * KNN;
        double mean[4];
#pragma unroll
        for (int c = 0; c < 4; ++c) mean[c] = S1[c] / M;
        double E2[4][4];
        E2[0][0] = s2v[0]; E2[0][1] = E2[1][0] = s2v[1];
        E2[0][2] = E2[2][0] = s2v[2]; E2[0][3] = E2[3][0] = s2v[3];
        E2[1][1] = s2v[4]; E2[1][2] = E2[2][1] = s2v[5];
        E2[1][3] = E2[3][1] = s2v[6];
        E2[2][2] = s2v[7]; E2[2][3] = E2[3][2] = s2v[8];
        E2[3][3] = s2v[9];
        double w[4];
#pragma unroll
        for (int c = 0; c < 4; ++c) w[c] = (double)W[o * 4 + c];
        const double bo = (double)bias[o];
        double mu = bo;
#pragma unroll
        for (int c = 0; c < 4; ++c) mu += w[c] * mean[c];
        double var = 0.0;
#pragma unroll
        for (int c = 0; c < 4; ++c)
#pragma unroll
            for (int c2 = 0; c2 < 4; ++c2)
                var += w[c] * w[c2] * (E2[c][c2] / M - mean[c] * mean[c2]);
        const double scale = (double)gamma[o] / sqrt(var + 1e-5);
#pragma unroll
        for (int c = 0; c < 4; ++c) sWp[o][c] = (float)(w[c] * scale);
        sbp[o] = (float)((bo - mu) * scale + (double)beta[o]);
    }
    __syncthreads();

    const int t  = threadIdx.x;
    const int gq = blockIdx.x * (BLK / 4) + (t >> 2);  // global query
    const int b  = gq / NP, n = gq % NP;
    const int c0 = (t & 3) * 16;                       // my 16 channels
    const float* pb = pos + (size_t)b * NP * 3;
    const float qx = pb[3 * n], qy = pb[3 * n + 1], qz = pb[3 * n + 2];

    float fx[KNN], fy[KNN], fz[KNN], fd[KNN];
    const unsigned short* ip = idx_in + (size_t)gq * KNN;
#pragma unroll
    for (int j = 0; j < KNN; ++j) {
        const int m = ip[j];
        const float dx = __fsub_rn(pb[3 * m], qx);
        const float dy = __fsub_rn(pb[3 * m + 1], qy);
        const float dz = __fsub_rn(pb[3 * m + 2], qz);
        fx[j] = dx; fy[j] = dy; fz[j] = dz;
        fd[j] = sqrtf(__fadd_rn(
            __fadd_rn(__fmul_rn(dx, dx), __fmul_rn(dy, dy)), __fmul_rn(dz, dz)));
    }

    float* ob = out + (size_t)gq * COUT + c0;
    const float inv = 1.0f / (float)KNN;
#pragma unroll
    for (int o = 0; o < 16; o += 4) {
        float acc[4];
#pragma unroll
        for (int qq = 0; qq < 4; ++qq) {
            const float w0 = sWp[c0 + o + qq][0], w1 = sWp[c0 + o + qq][1];
            const float w2 = sWp[c0 + o + qq][2], w3 = sWp[c0 + o + qq][3];
            const float bb = sbp[c0 + o + qq];
            float a = 0.f;
#pragma unroll
            for (int j = 0; j < KNN; ++j) {
                float y = fmaf(fx[j], w0,
                          fmaf(fy[j], w1, fmaf(fz[j], w2, fmaf(fd[j], w3, bb))));
                a += fmaxf(y, 0.f);
            }
            acc[qq] = a * inv;
        }
        float4 p = {acc[0], acc[1], acc[2], acc[3]};
        *reinterpret_cast<float4*>(ob + o) = p;
    }
}

extern "C" void kernel_launch(void* const* d_in, const int* in_sizes, int n_in,
                              void* d_out, int out_size, void* d_ws, size_t ws_size,
                              hipStream_t stream) {
    (void)in_sizes; (void)n_in; (void)out_size; (void)ws_size;
    const float* pos   = (const float*)d_in[1];   // d_in[0] = x (unused by math)
    const float* W     = (const float*)d_in[2];
    const float* bias  = (const float*)d_in[3];
    const float* gamma = (const float*)d_in[4];
    const float* beta  = (const float*)d_in[5];
    float* out = (float*)d_out;

    float* mom = (float*)d_ws;                                   // 14 floats
    unsigned short* idxws = (unsigned short*)((char*)d_ws + 64); // 1.31 MB

    hipMemsetAsync(mom, 0, NMOM * sizeof(float), stream);
    knn_kernel<<<NBLK1, BLK, 0, stream>>>(pos, idxws, mom);
    out_kernel<<<NBLK2, BLK, 0, stream>>>(pos, W, bias, gamma, beta,
                                          idxws, mom, out);
}

// Round 12
// 639.044 us; speedup vs baseline: 3.0203x; 1.0210x over previous
//
#include <hip/hip_runtime.h>

#define NB    8       // batches
#define NP    4096    // points per batch
#define KNN   20      // neighbors
#define COUT  64      // output channels
#define S     4       // candidate splits per query  (ROUND-11 VERIFIED CONFIG)
#define BLK   256     // threads per block (4 waves)
#define QPB   (BLK / S)          // 64 queries per block
#define BPB   (NP / QPB)         // 64 blocks per batch
#define NBLK1 (NB * BPB)         // 512 blocks
#define NBLK2 ((NB * NP * 4) / BLK)   // 512 blocks (4 threads per query)
#define NMOM  14
#define LCAP  32      // padded list length for bitonic merge
#define FBIG  3.402823466e38f

typedef unsigned long long u64;
typedef unsigned int u32;

// strict-< sorted insert (ascending), insert-after-equals == lax.top_k's
// lowest-index-first tie-break (verified rounds 4/6/8/11). d=FBIG -> no-op.
__device__ __forceinline__ void ins20(float d, u32 mi,
                                      float* __restrict__ bd,
                                      u32* __restrict__ bi) {
#pragma unroll
    for (int j = KNN - 1; j >= 1; --j) {
        const bool sh  = d < bd[j - 1];
        const bool in_ = !sh && (d < bd[j]);
        bi[j] = sh ? bi[j - 1] : (in_ ? mi : bi[j]);
        bd[j] = fminf(fmaxf(bd[j - 1], d), bd[j]);   // med3
    }
    if (d < bd[0]) { bi[0] = mi; bd[0] = d; }
}

// ---------------- Kernel 1: KNN (round-11 + group-min bound) -------------
__global__ __launch_bounds__(BLK, 2)
void knn_kernel(const float* __restrict__ pos,
                unsigned short* __restrict__ idx_out,
                float* __restrict__ mom) {
    __shared__ float4 sp[NP];                      // 64 KB: (x, y, z, csq)

    const int b = blockIdx.x / BPB;
    const int t = threadIdx.x;
    const int s = t & (S - 1);                     // my split
    const int n = (blockIdx.x % BPB) * QPB + (t >> 2);   // my query
    const float* pb = pos + (size_t)b * NP * 3;

    // stage pos[b]; csq computed with the reference's exact op sequence
    for (int i = t; i < NP; i += BLK) {
        const float x = pb[3 * i], y = pb[3 * i + 1], z = pb[3 * i + 2];
        const float csq = __fadd_rn(
            __fadd_rn(__fmul_rn(x, x), __fmul_rn(y, y)), __fmul_rn(z, z));
        sp[i] = make_float4(x, y, z, csq);
    }
    __syncthreads();

    const float4 q = sp[n];                        // qx,qy,qz,qsq (same bits)

    float bd[KNN];
    u32   bi[KNN];
#pragma unroll
    for (int j = 0; j < KNN; ++j) { bd[j] = FBIG; bi[j] = 0xFFFu; }
    float gb = FBIG;                               // group-min bound
    float b0d = 0.f, b1d = 0.f; u32 b0i = 0, b1i = 0; int cnt = 0;

#pragma unroll 4
    for (int i = 0; i < NP / S; ++i) {
        const int m = (i << 2) | s;
        const float4 c = sp[m];                    // 4 distinct addrs: broadcast
        const float dot = fmaf(q.z, c.z, fmaf(q.y, c.y, __fmul_rn(q.x, c.x)));
        const float d2  = __fsub_rn(__fadd_rn(q.w, c.w), __fmul_rn(2.0f, dot));
        // <= REQUIRED with a cross-lane bound: rejection must mean d2 is
        // STRICTLY above a full 20-list (20 strictly-better witnesses),
        // making it index-independent. Boundary ties go through own ins20.
        const bool acc = (m != n) && (d2 <= gb);
        const bool a0 = acc && (cnt == 0);
        const bool a1 = acc && (cnt == 1);
        b0d = a0 ? d2 : b0d;  b0i = a0 ? (u32)m : b0i;
        b1d = a1 ? d2 : b1d;  b1i = a1 ? (u32)m : b1i;
        cnt += (int)acc;
        if (__ballot(cnt == 2)) {                  // wave-wide amortized flush
            ins20(cnt >= 1 ? b0d : FBIG, b0i, bd, bi);
            ins20(cnt == 2 ? b1d : FBIG, b1i, bd, bi);
            cnt = 0;
            float g = bd[KNN - 1];                 // share bound across group
            g = fminf(g, __shfl_xor(g, 1));
            g = fminf(g, __shfl_xor(g, 2));
            gb = g;                                // stale-between-flushes: safe
        }
    }
    // drain pending
    ins20(cnt >= 1 ? b0d : FBIG, b0i, bd, bi);
    ins20(cnt == 2 ? b1d : FBIG, b1i, bd, bi);

    // build merge keys: order-preserving float->uint flip,
    // idx in low 12 bits = lowest-index-first ties (verified rounds 7/8/11)
    u64 key[LCAP];
#pragma unroll
    for (int j = 0; j < KNN; ++j) {
        u32 fb = __float_as_uint(bd[j]);
        fb ^= (u32)((int)fb >> 31) | 0x80000000u;
        key[j] = ((u64)fb << 12) | bi[j];
    }
#pragma unroll
    for (int j = KNN; j < LCAP; ++j) key[j] = ~0ull;

    // merge 4 split lists across lanes (round-7/8/11-verified bitonic merge)
#pragma unroll
    for (int r = 1; r <= 2; r <<= 1) {
#pragma unroll
        for (int j = 0; j < LCAP / 2; ++j) {
            const int k2 = LCAP - 1 - j;
            const u64 pa = (u64)__shfl_xor((long long)key[k2], r);
            const u64 pc = (u64)__shfl_xor((long long)key[j],  r);
            key[j]  = key[j]  < pa ? key[j]  : pa;
            key[k2] = key[k2] < pc ? key[k2] : pc;
        }
#pragma unroll
        for (int d = 16; d >= 1; d >>= 1) {
#pragma unroll
            for (int j = 0; j < LCAP; ++j) {
                if ((j & d) == 0) {
                    const u64 x = key[j], y = key[j + d];
                    key[j]     = x < y ? x : y;
                    key[j + d] = x < y ? y : x;
                }
            }
        }
    }

    // static-j epilogue (round-11 verified; no dynamic reg indexing)
    unsigned short* ip = idx_out + ((size_t)b * NP + n) * KNN;
    float s1x = 0, s1y = 0, s1z = 0, s1d = 0;
    float mxx = 0, mxy = 0, mxz = 0, mxd = 0;
    float myy = 0, myz = 0, myd = 0;
    float mzz = 0, mzd = 0, mdd = 0;
#pragma unroll
    for (int j = 0; j < KNN; ++j) {
        const int m = (int)(key[j] & 0xFFFull);
        if ((j & 3) == s) ip[j] = (unsigned short)m;   // one lane per j
        const float4 c = sp[m];
        const float dx = __fsub_rn(c.x, q.x);
        const float dy = __fsub_rn(c.y, q.y);
        const float dz = __fsub_rn(c.z, q.z);
        const float dd = sqrtf(__fadd_rn(
            __fadd_rn(__fmul_rn(dx, dx), __fmul_rn(dy, dy)), __fmul_rn(dz, dz)));
        s1x += dx; s1y += dy; s1z += dz; s1d += dd;
        mxx += dx * dx; mxy += dx * dy; mxz += dx * dz; mxd += dx * dd;
        myy += dy * dy; myz += dy * dz; myd += dy * dd;
        mzz += dz * dz; mzd += dz * dd; mdd += dd * dd;
    }
    {
        // every query counted 4x (once per split lane) -> exact /4 after reduce
        float vals[NMOM] = {s1x, s1y, s1z, s1d,
                            mxx, mxy, mxz, mxd, myy, myz, myd, mzz, mzd, mdd};
#pragma unroll
        for (int tt = 0; tt < NMOM; ++tt) {
            float v = vals[tt];
#pragma unroll
            for (int off = 32; off > 0; off >>= 1) v += __shfl_down(v, off);
            if ((t & 63) == 0) atomicAdd(&mom[tt], v * 0.25f);
        }
    }
}

// ---------------- Kernel 2: round-8/11 verbatim --------------------------
__global__ __launch_bounds__(BLK)
void out_kernel(const float* __restrict__ pos,
                const float* __restrict__ W,
                const float* __restrict__ bias,
                const float* __restrict__ gamma,
                const float* __restrict__ beta,
                const unsigned short* __restrict__ idx_in,
                const float* __restrict__ mom,
                float* __restrict__ out) {
    __shared__ float sWp[COUT][4];
    __shared__ float sbp[COUT];

    if (threadIdx.x < COUT) {
        const int o = threadIdx.x;
        double S1[4], s2v[10];
#pragma unroll
        for (int tt = 0; tt < 4; ++tt)  S1[tt]  = (double)mom[tt];
#pragma unroll
        for (int tt = 0; tt < 10; ++tt) s2v[tt] = (double)mom[4 + tt];
        const double M = (double)NB * NP * KNN;
        double mean[4];
#pragma unroll
        for (int c = 0; c < 4; ++c) mean[c] = S1[c] / M;
        double E2[4][4];
        E2[0][0] = s2v[0]; E2[0][1] = E2[1][0] = s2v[1];
        E2[0][2] = E2[2][0] = s2v[2]; E2[0][3] = E2[3][0] = s2v[3];
        E2[1][1] = s2v[4]; E2[1][2] = E2[2][1] = s2v[5];
        E2[1][3] = E2[3][1] = s2v[6];
        E2[2][2] = s2v[7]; E2[2][3] = E2[3][2] = s2v[8];
        E2[3][3] = s2v[9];
        double w[4];
#pragma unroll
        for (int c = 0; c < 4; ++c) w[c] = (double)W[o * 4 + c];
        const double bo = (double)bias[o];
        double mu = bo;
#pragma unroll
        for (int c = 0; c < 4; ++c) mu += w[c] * mean[c];
        double var = 0.0;
#pragma unroll
        for (int c = 0; c < 4; ++c)
#pragma unroll
            for (int c2 = 0; c2 < 4; ++c2)
                var += w[c] * w[c2] * (E2[c][c2] / M - mean[c] * mean[c2]);
        const double scale = (double)gamma[o] / sqrt(var + 1e-5);
#pragma unroll
        for (int c = 0; c < 4; ++c) sWp[o][c] = (float)(w[c] * scale);
        sbp[o] = (float)((bo - mu) * scale + (double)beta[o]);
    }
    __syncthreads();

    const int t  = threadIdx.x;
    const int gq = blockIdx.x * (BLK / 4) + (t >> 2);  // global query
    const int b  = gq / NP, n = gq % NP;
    const int c0 = (t & 3) * 16;                       // my 16 channels
    const float* pb = pos + (size_t)b * NP * 3;
    const float qx = pb[3 * n], qy = pb[3 * n + 1], qz = pb[3 * n + 2];

    float fx[KNN], fy[KNN], fz[KNN], fd[KNN];
    const unsigned short* ip = idx_in + (size_t)gq * KNN;
#pragma unroll
    for (int j = 0; j < KNN; ++j) {
        const int m = ip[j];
        const float dx = __fsub_rn(pb[3 * m], qx);
        const float dy = __fsub_rn(pb[3 * m + 1], qy);
        const float dz = __fsub_rn(pb[3 * m + 2], qz);
        fx[j] = dx; fy[j] = dy; fz[j] = dz;
        fd[j] = sqrtf(__fadd_rn(
            __fadd_rn(__fmul_rn(dx, dx), __fmul_rn(dy, dy)), __fmul_rn(dz, dz)));
    }

    float* ob = out + (size_t)gq * COUT + c0;
    const float inv = 1.0f / (float)KNN;
#pragma unroll
    for (int o = 0; o < 16; o += 4) {
        float acc[4];
#pragma unroll
        for (int qq = 0; qq < 4; ++qq) {
            const float w0 = sWp[c0 + o + qq][0], w1 = sWp[c0 + o + qq][1];
            const float w2 = sWp[c0 + o + qq][2], w3 = sWp[c0 + o + qq][3];
            const float bb = sbp[c0 + o + qq];
            float a = 0.f;
#pragma unroll
            for (int j = 0; j < KNN; ++j) {
                float y = fmaf(fx[j], w0,
                          fmaf(fy[j], w1, fmaf(fz[j], w2, fmaf(fd[j], w3, bb))));
                a += fmaxf(y, 0.f);
            }
            acc[qq] = a * inv;
        }
        float4 p = {acc[0], acc[1], acc[2], acc[3]};
        *reinterpret_cast<float4*>(ob + o) = p;
    }
}

extern "C" void kernel_launch(void* const* d_in, const int* in_sizes, int n_in,
                              void* d_out, int out_size, void* d_ws, size_t ws_size,
                              hipStream_t stream) {
    (void)in_sizes; (void)n_in; (void)out_size; (void)ws_size;
    const float* pos   = (const float*)d_in[1];   // d_in[0] = x (unused by math)
    const float* W     = (const float*)d_in[2];
    const float* bias  = (const float*)d_in[3];
    const float* gamma = (const float*)d_in[4];
    const float* beta  = (const float*)d_in[5];
    float* out = (float*)d_out;

    float* mom = (float*)d_ws;                                   // 14 floats
    unsigned short* idxws = (unsigned short*)((char*)d_ws + 64); // 1.31 MB

    hipMemsetAsync(mom, 0, NMOM * sizeof(float), stream);
    knn_kernel<<<NBLK1, BLK, 0, stream>>>(pos, idxws, mom);
    out_kernel<<<NBLK2, BLK, 0, stream>>>(pos, W, bias, gamma, beta,
                                          idxws, mom, out);
}

// Round 16
// 614.370 us; speedup vs baseline: 3.1416x; 1.0402x over previous
//
#include <hip/hip_runtime.h>

#define NB    8       // batches
#define NP    4096    // points per batch
#define KNN   20      // neighbors
#define COUT  64      // output channels
#define S     4       // candidate splits per query
#define BLK   256     // threads per block (4 waves)
#define QPB   (BLK / S)          // 64 queries per block
#define BPB   (NP / QPB)         // 64 blocks per batch
#define NBLK1 (NB * BPB)         // 512 blocks
#define NBLK2 ((NB * NP * 4) / BLK)   // 512 blocks (4 threads per query)
#define NMOM  14
#define LCAP  32      // padded list length for bitonic merge
#define FBIG  3.402823466e38f

typedef unsigned long long u64;
typedef unsigned int u32;

// strict-< sorted insert (ascending), insert-after-equals == lax.top_k's
// lowest-index-first tie-break (verified rounds 4/6/8/11/12). d=FBIG -> no-op.
__device__ __forceinline__ void ins20(float d, u32 mi,
                                      float* __restrict__ bd,
                                      u32* __restrict__ bi) {
#pragma unroll
    for (int j = KNN - 1; j >= 1; --j) {
        const bool sh  = d < bd[j - 1];
        const bool in_ = !sh && (d < bd[j]);
        bi[j] = sh ? bi[j - 1] : (in_ ? mi : bi[j]);
        bd[j] = fminf(fmaxf(bd[j - 1], d), bd[j]);   // med3
    }
    if (d < bd[0]) { bi[0] = mi; bd[0] = d; }
}

// ---------------- Kernel 1: KNN (r12 base + depth-4 register buffer) -----
__global__ __launch_bounds__(BLK, 2)
void knn_kernel(const float* __restrict__ pos,
                unsigned short* __restrict__ idx_out,
                float* __restrict__ mom) {
    __shared__ float4 sp[NP];                      // 64 KB: (x, y, z, csq)

    const int b = blockIdx.x / BPB;
    const int t = threadIdx.x;
    const int s = t & (S - 1);                     // my split
    const int n = (blockIdx.x % BPB) * QPB + (t >> 2);   // my query
    const float* pb = pos + (size_t)b * NP * 3;

    // stage pos[b]; csq computed with the reference's exact op sequence
    for (int i = t; i < NP; i += BLK) {
        const float x = pb[3 * i], y = pb[3 * i + 1], z = pb[3 * i + 2];
        const float csq = __fadd_rn(
            __fadd_rn(__fmul_rn(x, x), __fmul_rn(y, y)), __fmul_rn(z, z));
        sp[i] = make_float4(x, y, z, csq);
    }
    __syncthreads();

    const float4 q = sp[n];                        // qx,qy,qz,qsq (same bits)

    float bd[KNN];
    u32   bi[KNN];
#pragma unroll
    for (int j = 0; j < KNN; ++j) { bd[j] = FBIG; bi[j] = 0xFFFu; }
    float gb = FBIG;                               // group-min bound (r12-verified)
    float p0d = 0.f, p1d = 0.f, p2d = 0.f, p3d = 0.f;
    u32   p0i = 0, p1i = 0, p2i = 0, p3i = 0;
    int   cnt = 0;

#pragma unroll 2
    for (int i = 0; i < NP / S; ++i) {
        const int m = (i << 2) | s;
        const float4 c = sp[m];                    // 4 distinct addrs: broadcast
        const float dot = fmaf(q.z, c.z, fmaf(q.y, c.y, __fmul_rn(q.x, c.x)));
        const float d2  = __fsub_rn(__fadd_rn(q.w, c.w), __fmul_rn(2.0f, dot));
        // <=: rejection requires 20 STRICTLY better witnesses (index-free);
        // boundary cases flow through own-lane ins20 (exact). (r12-verified)
        const bool acc = (m != n) && (d2 <= gb);
        const bool a0 = acc && (cnt == 0), a1 = acc && (cnt == 1);
        const bool a2 = acc && (cnt == 2), a3 = acc && (cnt == 3);
        p0d = a0 ? d2 : p0d;  p0i = a0 ? (u32)m : p0i;
        p1d = a1 ? d2 : p1d;  p1i = a1 ? (u32)m : p1i;
        p2d = a2 ? d2 : p2d;  p2i = a2 ? (u32)m : p2i;
        p3d = a3 ? d2 : p3d;  p3i = a3 ? (u32)m : p3i;
        cnt += (int)acc;
        if (__ballot(cnt == 4)) {                  // amortized wave-wide flush
            ins20(cnt >= 1 ? p0d : FBIG, p0i, bd, bi);
            ins20(cnt >= 2 ? p1d : FBIG, p1i, bd, bi);
            ins20(cnt >= 3 ? p2d : FBIG, p2i, bd, bi);
            ins20(cnt >= 4 ? p3d : FBIG, p3i, bd, bi);
            cnt = 0;
            float g = bd[KNN - 1];                 // refresh group bound
            g = fminf(g, __shfl_xor(g, 1));
            g = fminf(g, __shfl_xor(g, 2));
            gb = g;
        }
    }
    // drain pending
    ins20(cnt >= 1 ? p0d : FBIG, p0i, bd, bi);
    ins20(cnt >= 2 ? p1d : FBIG, p1i, bd, bi);
    ins20(cnt >= 3 ? p2d : FBIG, p2i, bd, bi);
    ins20(cnt >= 4 ? p3d : FBIG, p3i, bd, bi);

    // build merge keys: order-preserving float->uint flip,
    // idx in low 12 bits = lowest-index-first ties (verified r7/8/11/12)
    u64 key[LCAP];
#pragma unroll
    for (int j = 0; j < KNN; ++j) {
        u32 fb = __float_as_uint(bd[j]);
        fb ^= (u32)((int)fb >> 31) | 0x80000000u;
        key[j] = ((u64)fb << 12) | bi[j];
    }
#pragma unroll
    for (int j = KNN; j < LCAP; ++j) key[j] = ~0ull;

    // merge 4 split lists across lanes (verified bitonic merge)
#pragma unroll
    for (int r = 1; r <= 2; r <<= 1) {
#pragma unroll
        for (int j = 0; j < LCAP / 2; ++j) {
            const int k2 = LCAP - 1 - j;
            const u64 pa = (u64)__shfl_xor((long long)key[k2], r);
            const u64 pc = (u64)__shfl_xor((long long)key[j],  r);
            key[j]  = key[j]  < pa ? key[j]  : pa;
            key[k2] = key[k2] < pc ? key[k2] : pc;
        }
#pragma unroll
        for (int d = 16; d >= 1; d >>= 1) {
#pragma unroll
            for (int j = 0; j < LCAP; ++j) {
                if ((j & d) == 0) {
                    const u64 x = key[j], y = key[j + d];
                    key[j]     = x < y ? x : y;
                    key[j + d] = x < y ? y : x;
                }
            }
        }
    }

    // static-j epilogue (verified; no dynamic reg indexing)
    unsigned short* ip = idx_out + ((size_t)b * NP + n) * KNN;
    float s1x = 0, s1y = 0, s1z = 0, s1d = 0;
    float mxx = 0, mxy = 0, mxz = 0, mxd = 0;
    float myy = 0, myz = 0, myd = 0;
    float mzz = 0, mzd = 0, mdd = 0;
#pragma unroll
    for (int j = 0; j < KNN; ++j) {
        const int m = (int)(key[j] & 0xFFFull);
        if ((j & 3) == s) ip[j] = (unsigned short)m;   // one lane per j
        const float4 c = sp[m];
        const float dx = __fsub_rn(c.x, q.x);
        const float dy = __fsub_rn(c.y, q.y);
        const float dz = __fsub_rn(c.z, q.z);
        const float dd = sqrtf(__fadd_rn(
            __fadd_rn(__fmul_rn(dx, dx), __fmul_rn(dy, dy)), __fmul_rn(dz, dz)));
        s1x += dx; s1y += dy; s1z += dz; s1d += dd;
        mxx += dx * dx; mxy += dx * dy; mxz += dx * dz; mxd += dx * dd;
        myy += dy * dy; myz += dy * dz; myd += dy * dd;
        mzz += dz * dz; mzd += dz * dd; mdd += dd * dd;
    }
    {
        // every query counted 4x (once per split lane) -> exact /4 after reduce
        float vals[NMOM] = {s1x, s1y, s1z, s1d,
                            mxx, mxy, mxz, mxd, myy, myz, myd, mzz, mzd, mdd};
#pragma unroll
        for (int tt = 0; tt < NMOM; ++tt) {
            float v = vals[tt];
#pragma unroll
            for (int off = 32; off > 0; off >>= 1) v += __shfl_down(v, off);
            if ((t & 63) == 0) atomicAdd(&mom[tt], v * 0.25f);
        }
    }
}

// ---------------- Kernel 2: round-8/11/12 verbatim -----------------------
__global__ __launch_bounds__(BLK)
void out_kernel(const float* __restrict__ pos,
                const float* __restrict__ W,
                const float* __restrict__ bias,
                const float* __restrict__ gamma,
                const float* __restrict__ beta,
                const unsigned short* __restrict__ idx_in,
                const float* __restrict__ mom,
                float* __restrict__ out) {
    __shared__ float sWp[COUT][4];
    __shared__ float sbp[COUT];

    if (threadIdx.x < COUT) {
        const int o = threadIdx.x;
        double S1[4], s2v[10];
#pragma unroll
        for (int tt = 0; tt < 4; ++tt)  S1[tt]  = (double)mom[tt];
#pragma unroll
        for (int tt = 0; tt < 10; ++tt) s2v[tt] = (double)mom[4 + tt];
        const double M = (double)NB * NP * KNN;
        double mean[4];
#pragma unroll
        for (int c = 0; c < 4; ++c) mean[c] = S1[c] / M;
        double E2[4][4];
        E2[0][0] = s2v[0]; E2[0][1] = E2[1][0] = s2v[1];
        E2[0][2] = E2[2][0] = s2v[2]; E2[0][3] = E2[3][0] = s2v[3];
        E2[1][1] = s2v[4]; E2[1][2] = E2[2][1] = s2v[5];
        E2[1][3] = E2[3][1] = s2v[6];
        E2[2][2] = s2v[7]; E2[2][3] = E2[3][2] = s2v[8];
        E2[3][3] = s2v[9];
        double w[4];
#pragma unroll
        for (int c = 0; c < 4; ++c) w[c] = (double)W[o * 4 + c];
        const double bo = (double)bias[o];
        double mu = bo;
#pragma unroll
        for (int c = 0; c < 4; ++c) mu += w[c] * mean[c];
        double var = 0.0;
#pragma unroll
        for (int c = 0; c < 4; ++c)
#pragma unroll
            for (int c2 = 0; c2 < 4; ++c2)
                var += w[c] * w[c2] * (E2[c][c2] / M - mean[c] * mean[c2]);
        const double scale = (double)gamma[o] / sqrt(var + 1e-5);
#pragma unroll
        for (int c = 0; c < 4; ++c) sWp[o][c] = (float)(w[c] * scale);
        sbp[o] = (float)((bo - mu) * scale + (double)beta[o]);
    }
    __syncthreads();

    const int t  = threadIdx.x;
    const int gq = blockIdx.x * (BLK / 4) + (t >> 2);  // global query
    const int b  = gq / NP, n = gq % NP;
    const int c0 = (t & 3) * 16;                       // my 16 channels
    const float* pb = pos + (size_t)b * NP * 3;
    const float qx = pb[3 * n], qy = pb[3 * n + 1], qz = pb[3 * n + 2];

    float fx[KNN], fy[KNN], fz[KNN], fd[KNN];
    const unsigned short* ip = idx_in + (size_t)gq * KNN;
#pragma unroll
    for (int j = 0; j < KNN; ++j) {
        const int m = ip[j];
        const float dx = __fsub_rn(pb[3 * m], qx);
        const float dy = __fsub_rn(pb[3 * m + 1], qy);
        const float dz = __fsub_rn(pb[3 * m + 2], qz);
        fx[j] = dx; fy[j] = dy; fz[j] = dz;
        fd[j] = sqrtf(__fadd_rn(
            __fadd_rn(__fmul_rn(dx, dx), __fmul_rn(dy, dy)), __fmul_rn(dz, dz)));
    }

    float* ob = out + (size_t)gq * COUT + c0;
    const float inv = 1.0f / (float)KNN;
#pragma unroll
    for (int o = 0; o < 16; o += 4) {
        float acc[4];
#pragma unroll
        for (int qq = 0; qq < 4; ++qq) {
            const float w0 = sWp[c0 + o + qq][0], w1 = sWp[c0 + o + qq][1];
            const float w2 = sWp[c0 + o + qq][2], w3 = sWp[c0 + o + qq][3];
            const float bb = sbp[c0 + o + qq];
            float a = 0.f;
#pragma unroll
            for (int j = 0; j < KNN; ++j) {
                float y = fmaf(fx[j], w0,
                          fmaf(fy[j], w1, fmaf(fz[j], w2, fmaf(fd[j], w3, bb))));
                a += fmaxf(y, 0.f);
            }
            acc[qq] = a * inv;
        }
        float4 p = {acc[0], acc[1], acc[2], acc[3]};
        *reinterpret_cast<float4*>(ob + o) = p;
    }
}

extern "C" void kernel_launch(void* const* d_in, const int* in_sizes, int n_in,
                              void* d_out, int out_size, void* d_ws, size_t ws_size,
                              hipStream_t stream) {
    (void)in_sizes; (void)n_in; (void)out_size; (void)ws_size;
    const float* pos   = (const float*)d_in[1];   // d_in[0] = x (unused by math)
    const float* W     = (const float*)d_in[2];
    const float* bias  = (const float*)d_in[3];
    const float* gamma = (const float*)d_in[4];
    const float* beta  = (const float*)d_in[5];
    float* out = (float*)d_out;

    float* mom = (float*)d_ws;                                   // 14 floats
    unsigned short* idxws = (unsigned short*)((char*)d_ws + 64); // 1.31 MB

    hipMemsetAsync(mom, 0, NMOM * sizeof(float), stream);
    knn_kernel<<<NBLK1, BLK, 0, stream>>>(pos, idxws, mom);
    out_kernel<<<NBLK2, BLK, 0, stream>>>(pos, W, bias, gamma, beta,
                                          idxws, mom, out);
}